// Round 7
// baseline (15920.345 us; speedup 1.0000x reference)
//
#include <hip/hip_runtime.h>
#include <hip/hip_bf16.h>

typedef __bf16 bf16x8 __attribute__((ext_vector_type(8)));
typedef float  f32x4  __attribute__((ext_vector_type(4)));
typedef float  f32x8  __attribute__((ext_vector_type(8)));
typedef int    i32x4  __attribute__((ext_vector_type(4)));

#define T_LEN 1024
#define DD    512
#define HH    512
#define NBLK  64     // 64 blocks x 8 h-cols = 512 = H

__device__ __forceinline__ f32x4 mfma16(bf16x8 a, bf16x8 b, f32x4 c) {
    return __builtin_amdgcn_mfma_f32_16x16x32_bf16(a, b, c, 0, 0, 0);
}
__device__ __forceinline__ float sigmf_(float v) { return 1.f / (1.f + __expf(-v)); }
__device__ __forceinline__ float tanhf_(float v) { return 1.f - 2.f / (1.f + __expf(2.f * v)); }
__device__ __forceinline__ bf16x8 cvt8(f32x8 v) {
    bf16x8 r;
    #pragma unroll
    for (int j = 0; j < 8; ++j) r[j] = (__bf16)v[j];
    return r;
}

// 16 coherent (sc1, LLC-served) 16-B fragment loads, ONE round-trip.
__device__ __forceinline__ void coh_load_frags(const unsigned short* p, i32x4 f[16]) {
    asm volatile(
        "global_load_dwordx4 %0, %16, off sc1\n\t"
        "global_load_dwordx4 %1, %16, off offset:64 sc1\n\t"
        "global_load_dwordx4 %2, %16, off offset:128 sc1\n\t"
        "global_load_dwordx4 %3, %16, off offset:192 sc1\n\t"
        "global_load_dwordx4 %4, %16, off offset:256 sc1\n\t"
        "global_load_dwordx4 %5, %16, off offset:320 sc1\n\t"
        "global_load_dwordx4 %6, %16, off offset:384 sc1\n\t"
        "global_load_dwordx4 %7, %16, off offset:448 sc1\n\t"
        "global_load_dwordx4 %8, %16, off offset:512 sc1\n\t"
        "global_load_dwordx4 %9, %16, off offset:576 sc1\n\t"
        "global_load_dwordx4 %10, %16, off offset:640 sc1\n\t"
        "global_load_dwordx4 %11, %16, off offset:704 sc1\n\t"
        "global_load_dwordx4 %12, %16, off offset:768 sc1\n\t"
        "global_load_dwordx4 %13, %16, off offset:832 sc1\n\t"
        "global_load_dwordx4 %14, %16, off offset:896 sc1\n\t"
        "global_load_dwordx4 %15, %16, off offset:960 sc1\n\t"
        "s_waitcnt vmcnt(0)"
        : "=&v"(f[0]), "=&v"(f[1]), "=&v"(f[2]), "=&v"(f[3]),
          "=&v"(f[4]), "=&v"(f[5]), "=&v"(f[6]), "=&v"(f[7]),
          "=&v"(f[8]), "=&v"(f[9]), "=&v"(f[10]), "=&v"(f[11]),
          "=&v"(f[12]), "=&v"(f[13]), "=&v"(f[14]), "=&v"(f[15])
        : "v"(p)
        : "memory");
}

// Data-is-the-flag: re-load the 16 frags until every 8-B atomic-store unit is
// visibly nonzero (stash values have +0 remapped to 0x0001; region was zeroed
// at launch; 8-B stores are all-or-nothing, so one u16 per unit suffices).
__device__ __forceinline__ void poll_frags(const unsigned short* p, i32x4 f[16]) {
    for (;;) {
        coh_load_frags(p, f);
        unsigned mn = 0xffffffffu;
        #pragma unroll
        for (int kk = 0; kk < 16; ++kk) {
            mn = min(mn, (unsigned)f[kk][0] & 0xffffu);   // lo u16 of first 8-B unit
            mn = min(mn, (unsigned)f[kk][2] & 0xffffu);   // lo u16 of second 8-B unit
        }
        if (__all((int)(mn != 0u))) break;
        __builtin_amdgcn_s_sleep(1);
    }
}

__device__ __forceinline__ void xpart_mfma(const float* xr, const bf16x8* wbh, const bf16x8* wbl,
                                           f32x4& ac0, f32x4& ac1, f32x4& ac2, f32x4& ac3) {
    #pragma unroll
    for (int kk = 0; kk < 16; ++kk) {
        bf16x8 av = cvt8(*(const f32x8*)(xr + kk * 32));
        if (kk & 1) { ac1 = mfma16(av, wbh[kk], ac1); ac3 = mfma16(av, wbl[kk], ac3); }
        else        { ac0 = mfma16(av, wbh[kk], ac0); ac2 = mfma16(av, wbl[kk], ac2); }
    }
}

// Round 13 = round 11 (flagless data-poll, verified 11563 us) + CALIBRATED
// SERIAL-DELAY PROBE: ~5k cycles of dependent FMAs inserted after the stores
// and before xpart, fenced with sched_barrier(0) so the scheduler cannot hide
// it under xpart/poll. Measures downstream wait slack:
//   dur +~0    -> >=2us/step slack in xpart/poll waits (store-visibility bound)
//   dur +2.1ms -> chain-bound at 2.4GHz (no slack)
//   dur +8ms   -> effective clock ~600MHz
__global__ void __launch_bounds__(256, 1)
lstm_pk(const float* __restrict__ x,    // (32,1024,512) fp32
        const float* __restrict__ h0,   // (32,512)
        const float* __restrict__ Wx,   // (512,2048)
        const float* __restrict__ Wh,   // (512,2048)
        const float* __restrict__ bias, // (2048)
        float* __restrict__ out,        // (32,1024,512) fp32, zeroed at launch
        unsigned short* __restrict__ ws16)  // 32x512 bf16 arena, zeroed at launch
{
    __shared__ float a_lds[32][36];     // pitch 36: both access phases <=2-way (free)

    const int tid  = threadIdx.x;
    const int blk  = blockIdx.x;
    const int hc0  = blk * 8;
    const int lane = tid & 63;
    const int wid  = tid >> 6;          // 4 waves: wid&1 = m-tile, wid>>1 = n-tile
    const int q    = lane >> 4;
    const int mrow = (wid & 1) * 16 + (lane & 15);
    const int bcol = (wid >> 1) * 16 + (lane & 15);
    const int gcol = (bcol >> 3) * HH + hc0 + (bcol & 7);

    // ---- one-time: weight B-frags, bf16 hi+lo split (error ~2^-17) ----
    bf16x8 wbh[32], wbl[32];
    #pragma unroll
    for (int kk = 0; kk < 32; ++kk) {
        const float* wsrc = (kk < 16) ? Wx : Wh;
        const int kb = (kk & 15) * 32 + q * 8;
        bf16x8 wh_, wl_;
        #pragma unroll
        for (int j = 0; j < 8; ++j) {
            float w = wsrc[(size_t)(kb + j) * (4 * HH) + gcol];
            __bf16 hi = (__bf16)w;
            wh_[j] = hi;
            wl_[j] = (__bf16)(w - (float)hi);
        }
        wbh[kk] = wh_; wbl[kk] = wl_;
    }

    // ---- gate-thread mapping: thread <-> (n = tid>>3, hcol = hc0 + (tid&7)) ----
    const int gn  = tid >> 3;
    const int glc = tid & 7;
    const float bi  = bias[0 * HH + hc0 + glc];
    const float bf_ = bias[1 * HH + hc0 + glc];
    const float bo  = bias[2 * HH + hc0 + glc];
    const float bg  = bias[3 * HH + hc0 + glc];
    float creg = 0.f;
    const size_t outoff = (size_t)gn * T_LEN * HH + hc0 + glc;

    const float* xrow0 = x + (size_t)mrow * T_LEN * DD + q * 8;
    // stash addressing (bf16 packed in first half of a future out[.,tt,.] row)
    unsigned short* u16out = (unsigned short*)out;
    const unsigned short* cbase =
        (const unsigned short*)out + 2 * ((size_t)mrow * T_LEN * HH) + q * 8;
    const size_t stash_w = 2 * ((size_t)gn * T_LEN * HH) + (hc0 + glc);
    // d_ws arena: 32 rows x 512 cols bf16 (same frag stride 64 B as the stash)
    const unsigned short* wsrd = ws16 + (size_t)mrow * HH + q * 8;
    const size_t ws_w = (size_t)gn * HH + (hc0 + glc);

    // prologue: x-part for t=0
    f32x4 ac0 = {0,0,0,0}, ac1 = {0,0,0,0}, ac2 = {0,0,0,0}, ac3 = {0,0,0,0};
    xpart_mfma(xrow0, wbh, wbl, ac0, ac1, ac2, ac3);

    #pragma unroll 1
    for (int t = 0; t < T_LEN; ++t) {
        // ---- h_{t-1} A-frags: poll the data itself (no flags) ----
        bf16x8 hfrag[16];
        if (t == 0) {
            #pragma unroll
            for (int kk = 0; kk < 16; ++kk)
                hfrag[kk] = cvt8(*(const f32x8*)(h0 + (size_t)mrow * HH + kk * 32 + q * 8));
        } else {
            i32x4 f[16];
            if (t < T_LEN - 1)
                poll_frags(cbase + 2 * (size_t)(t + 1) * HH, f);   // stash of h_{t-1}
            else
                poll_frags(wsrd, f);                               // h_{T-2} from arena
            #pragma unroll
            for (int kk = 0; kk < 16; ++kk) hfrag[kk] = *(bf16x8*)&f[kk];
        }

        // ---- h-part MFMAs (acc already holds x-part for this t) ----
        #pragma unroll
        for (int kk = 0; kk < 16; ++kk) {
            const int kw = 16 + kk;
            if (kw & 1) { ac1 = mfma16(hfrag[kk], wbh[kw], ac1); ac3 = mfma16(hfrag[kk], wbl[kw], ac3); }
            else        { ac0 = mfma16(hfrag[kk], wbh[kw], ac0); ac2 = mfma16(hfrag[kk], wbl[kw], ac2); }
        }

        // C/D layout [m89]: col = lane&15, row = quad*4 + reg (+ m-tile*16)
        f32x4 av4 = (ac0 + ac1) + (ac2 + ac3);
        __syncthreads();                 // (1) gates(t-1) done reading a_lds
        #pragma unroll
        for (int r = 0; r < 4; ++r)
            a_lds[(wid & 1) * 16 + q * 4 + r][bcol] = av4[r];
        __syncthreads();                 // (2) a_lds(t) published

        // ---- gates ----
        float ai = a_lds[gn][glc]      + bi;
        float af = a_lds[gn][8 + glc]  + bf_;
        float ao = a_lds[gn][16 + glc] + bo;
        float ag = a_lds[gn][24 + glc] + bg;
        float iv = sigmf_(ai), fv = sigmf_(af), ov = sigmf_(ao);
        float gv = tanhf_(ag);
        creg = fv * creg + iv * gv;
        float hv = ov * tanhf_(creg);

        // ---- pack (intra-wave shuffles; glc = tid&7 so partners same wave) ----
        unsigned hvu = __float_as_uint(hv);
        unsigned long long opair =
            ((unsigned long long)__shfl_xor(hvu, 1) << 32) | (unsigned long long)hvu;
        __bf16 hb = (__bf16)hv;
        unsigned short hus = *(unsigned short*)&hb;
        if (hus == 0) hus = 1;           // +0 -> smallest denormal (poll sentinel)
        unsigned hu = (unsigned)hus;
        unsigned hp = (__shfl_xor(hu, 1) << 16) | hu;
        unsigned long long hq =
            ((unsigned long long)__shfl_xor(hp, 2) << 32) | (unsigned long long)hp;

        // ---- fire-and-forget stores (no drains, no flags) ----
        if ((glc & 1) == 0)
            __hip_atomic_store((unsigned long long*)(out + outoff + (size_t)t * HH),
                               opair, __ATOMIC_RELAXED, __HIP_MEMORY_SCOPE_AGENT);
        if ((glc & 3) == 0) {
            if (t < T_LEN - 2)           // stash h_t into out[:, t+2, :]
                __hip_atomic_store((unsigned long long*)(u16out + stash_w + 2 * (size_t)(t + 2) * HH),
                                   hq, __ATOMIC_RELAXED, __HIP_MEMORY_SCOPE_AGENT);
            else if (t == T_LEN - 2)     // stash h_{T-2} into the d_ws arena
                __hip_atomic_store((unsigned long long*)(ws16 + ws_w),
                                   hq, __ATOMIC_RELAXED, __HIP_MEMORY_SCOPE_AGENT);
        }

        // ---- CALIBRATED SERIAL-DELAY PROBE: ~5k cyc dependent FMA chain ----
        // Fenced so it cannot overlap xpart/poll. Seeded by hv (fresh each
        // iter, can't hoist); sunk via asm (can't DCE). Does not touch memory.
        __builtin_amdgcn_sched_barrier(0);
        {
            float z = hv;
            #pragma unroll 1
            for (int d = 0; d < 128; ++d) {
                #pragma unroll
                for (int e = 0; e < 8; ++e)
                    z = __builtin_fmaf(z, 1.0000001f, 1e-20f);
            }
            asm volatile("" :: "v"(z));
        }
        __builtin_amdgcn_sched_barrier(0);

        // ---- x-part for t+1, overlapping other blocks' polls ----
        if (t + 1 < T_LEN) {
            ac0 = (f32x4){0,0,0,0}; ac1 = (f32x4){0,0,0,0};
            ac2 = (f32x4){0,0,0,0}; ac3 = (f32x4){0,0,0,0};
            xpart_mfma(xrow0 + (size_t)(t + 1) * DD, wbh, wbl, ac0, ac1, ac2, ac3);
        }
    }
}

extern "C" void kernel_launch(void* const* d_in, const int* in_sizes, int n_in,
                              void* d_out, int out_size, void* d_ws, size_t ws_size,
                              hipStream_t stream) {
    const float* x  = (const float*)d_in[0];
    const float* h0 = (const float*)d_in[1];
    const float* Wx = (const float*)d_in[2];
    const float* Wh = (const float*)d_in[3];
    const float* b  = (const float*)d_in[4];
    float* out = (float*)d_out;
    unsigned short* ws16 = (unsigned short*)d_ws;   // 32 KB arena

    // Self-contained zero-init: data-poll scheme requires stash bytes = 0.
    hipMemsetAsync(out, 0, (size_t)32 * T_LEN * HH * sizeof(float), stream);
    hipMemsetAsync(ws16, 0, (size_t)32 * HH * sizeof(unsigned short), stream);
    lstm_pk<<<dim3(NBLK), dim3(256), 0, stream>>>(x, h0, Wx, Wh, b, out, ws16);
}

// Round 8
// 5249.213 us; speedup vs baseline: 3.0329x; 3.0329x over previous
//
#include <hip/hip_runtime.h>
#include <hip/hip_bf16.h>

typedef __bf16 bf16x8 __attribute__((ext_vector_type(8)));
typedef float  f32x4  __attribute__((ext_vector_type(4)));
typedef float  f32x8  __attribute__((ext_vector_type(8)));
typedef int    i32x4  __attribute__((ext_vector_type(4)));

#define T_LEN 1024
#define DD    512
#define HH    512
#define NBLK  64     // 64 consumer blocks x 8 h-cols = 512 = H (+64 producers)
#define DEPTH 8      // ring depth (steps ahead); ring = 64*8*4KB = 2 MB in d_ws
#define FSTRIDE 8    // progress-word spacing: 8 uints = 32 B

__device__ __forceinline__ f32x4 mfma16(bf16x8 a, bf16x8 b, f32x4 c) {
    return __builtin_amdgcn_mfma_f32_16x16x32_bf16(a, b, c, 0, 0, 0);
}
__device__ __forceinline__ float sigmf_(float v) { return 1.f / (1.f + __expf(-v)); }
__device__ __forceinline__ float tanhf_(float v) { return 1.f - 2.f / (1.f + __expf(2.f * v)); }
__device__ __forceinline__ bf16x8 cvt8(f32x8 v) {
    bf16x8 r;
    #pragma unroll
    for (int j = 0; j < 8; ++j) r[j] = (__bf16)v[j];
    return r;
}

// Combined poll: 1 ring load + 16 h-frag loads, ONE round-trip, all sc1.
// Data-is-the-flag on BOTH streams: h-stash bf16 units (+0 remapped 0x0001)
// and ring f32 words (0x0 remapped 0x00000001). rv/f are asm outputs, so the
// compiler orders their uses after the trailing vmcnt(0).
__device__ __forceinline__ void poll17(const unsigned short* p, const float* rp,
                                       i32x4 f[16], i32x4* rv) {
    for (;;) {
        asm volatile(
            "global_load_dwordx4 %16, %18, off sc1\n\t"
            "global_load_dwordx4 %0, %17, off sc1\n\t"
            "global_load_dwordx4 %1, %17, off offset:64 sc1\n\t"
            "global_load_dwordx4 %2, %17, off offset:128 sc1\n\t"
            "global_load_dwordx4 %3, %17, off offset:192 sc1\n\t"
            "global_load_dwordx4 %4, %17, off offset:256 sc1\n\t"
            "global_load_dwordx4 %5, %17, off offset:320 sc1\n\t"
            "global_load_dwordx4 %6, %17, off offset:384 sc1\n\t"
            "global_load_dwordx4 %7, %17, off offset:448 sc1\n\t"
            "global_load_dwordx4 %8, %17, off offset:512 sc1\n\t"
            "global_load_dwordx4 %9, %17, off offset:576 sc1\n\t"
            "global_load_dwordx4 %10, %17, off offset:640 sc1\n\t"
            "global_load_dwordx4 %11, %17, off offset:704 sc1\n\t"
            "global_load_dwordx4 %12, %17, off offset:768 sc1\n\t"
            "global_load_dwordx4 %13, %17, off offset:832 sc1\n\t"
            "global_load_dwordx4 %14, %17, off offset:896 sc1\n\t"
            "global_load_dwordx4 %15, %17, off offset:960 sc1\n\t"
            "s_waitcnt vmcnt(0)"
            : "=&v"(f[0]), "=&v"(f[1]), "=&v"(f[2]), "=&v"(f[3]),
              "=&v"(f[4]), "=&v"(f[5]), "=&v"(f[6]), "=&v"(f[7]),
              "=&v"(f[8]), "=&v"(f[9]), "=&v"(f[10]), "=&v"(f[11]),
              "=&v"(f[12]), "=&v"(f[13]), "=&v"(f[14]), "=&v"(f[15]),
              "=&v"(*rv)
            : "v"(p), "v"(rp)
            : "memory");
        unsigned mn = 0xffffffffu;
        #pragma unroll
        for (int kk = 0; kk < 16; ++kk) {
            mn = min(mn, (unsigned)f[kk][0] & 0xffffu);   // lo u16 of 1st 8-B unit
            mn = min(mn, (unsigned)f[kk][2] & 0xffffu);   // lo u16 of 2nd 8-B unit
        }
        int ok = (mn != 0u) & ((*rv)[0] != 0) & ((*rv)[2] != 0);
        if (__all(ok)) break;
        __builtin_amdgcn_s_sleep(1);
    }
}

// ring-only poll (t==0: h comes from h0 input, only xW needs the ring)
__device__ __forceinline__ i32x4 poll_ring(const float* rp) {
    i32x4 rv;
    for (;;) {
        asm volatile(
            "global_load_dwordx4 %0, %1, off sc1\n\t"
            "s_waitcnt vmcnt(0)"
            : "=&v"(rv) : "v"(rp) : "memory");
        if (__all((rv[0] != 0) & (rv[2] != 0))) break;
        __builtin_amdgcn_s_sleep(1);
    }
    return rv;
}

__device__ __forceinline__ void xpart_mfma(const float* xr, const bf16x8* wbh, const bf16x8* wbl,
                                           f32x4& ac0, f32x4& ac1, f32x4& ac2, f32x4& ac3) {
    #pragma unroll
    for (int kk = 0; kk < 16; ++kk) {
        bf16x8 av = cvt8(*(const f32x8*)(xr + kk * 32));
        if (kk & 1) { ac1 = mfma16(av, wbh[kk], ac1); ac3 = mfma16(av, wbl[kk], ac3); }
        else        { ac0 = mfma16(av, wbh[kk], ac0); ac2 = mfma16(av, wbl[kk], ac2); }
    }
}

// Round 14: producer/consumer split. The r7 probe proved the step period is
// the block's own serial chain (zero downstream slack, eff. clock ~1 GHz), so
// xW — which has no recurrent dependence — moves to 64 dedicated producer
// blocks running DEPTH steps ahead through a zero-initialized ring in d_ws
// (data-is-the-flag, consumer re-zeroes slots after use). Consumer chain is
// now: 17-load poll (1 RTT) -> 32 h-MFMAs -> gates -> stores.
__global__ void __launch_bounds__(256, 1)
lstm_pk(const float* __restrict__ x,    // (32,1024,512) fp32
        const float* __restrict__ h0,   // (32,512)
        const float* __restrict__ Wx,   // (512,2048)
        const float* __restrict__ Wh,   // (512,2048)
        const float* __restrict__ bias, // (2048)
        float* __restrict__ out,        // (32,1024,512) fp32, zeroed at launch
        unsigned short* __restrict__ ws16,   // 32x512 bf16 arena (zeroed)
        unsigned* __restrict__ progress,     // 64 words, 32-B spaced (zeroed)
        float* __restrict__ ring)            // 64*DEPTH*1024 f32 (zeroed)
{
    __shared__ float a_lds[32][36];

    const int tid  = threadIdx.x;
    const bool isprod = (blockIdx.x >= NBLK);
    const int blk  = isprod ? (blockIdx.x - NBLK) : blockIdx.x;
    const int hc0  = blk * 8;
    const int lane = tid & 63;
    const int wid  = tid >> 6;          // 4 waves: wid&1 = m-tile, wid>>1 = n-tile
    const int q    = lane >> 4;
    const int mrow = (wid & 1) * 16 + (lane & 15);
    const int bcol = (wid >> 1) * 16 + (lane & 15);
    const int gcol = (bcol >> 3) * HH + hc0 + (bcol & 7);

    // ---- one-time: role-specific weight B-frags, bf16 hi+lo split ----
    const float* wsrc = isprod ? Wx : Wh;
    bf16x8 wbh[16], wbl[16];
    #pragma unroll
    for (int kk = 0; kk < 16; ++kk) {
        const int kb = kk * 32 + q * 8;
        bf16x8 wh_, wl_;
        #pragma unroll
        for (int j = 0; j < 8; ++j) {
            float w = wsrc[(size_t)(kb + j) * (4 * HH) + gcol];
            __bf16 hi = (__bf16)w;
            wh_[j] = hi;
            wl_[j] = (__bf16)(w - (float)hi);
        }
        wbh[kk] = wh_; wbl[kk] = wl_;
    }

    float* rbase = ring + (size_t)blk * DEPTH * 1024;

    // ================= producer role =================
    if (isprod) {
        const float* xrow0 = x + (size_t)mrow * T_LEN * DD + q * 8;
        unsigned last = 0;
        #pragma unroll 1
        for (int t = 0; t < T_LEN; ++t) {
            // throttle: slot t writable iff t < progress + DEPTH
            while (t >= (int)last + DEPTH) {
                last = __hip_atomic_load(progress + blk * FSTRIDE,
                                         __ATOMIC_RELAXED, __HIP_MEMORY_SCOPE_AGENT);
                if (t >= (int)last + DEPTH) __builtin_amdgcn_s_sleep(8);
            }
            f32x4 a0 = {0,0,0,0}, a1 = {0,0,0,0}, a2 = {0,0,0,0}, a3 = {0,0,0,0};
            xpart_mfma(xrow0 + (size_t)t * DD, wbh, wbl, a0, a1, a2, a3);
            f32x4 s = (a0 + a1) + (a2 + a3);
            unsigned u0 = __float_as_uint(s[0]); if (!u0) u0 = 1u;
            unsigned u1 = __float_as_uint(s[1]); if (!u1) u1 = 1u;
            unsigned u2 = __float_as_uint(s[2]); if (!u2) u2 = 1u;
            unsigned u3 = __float_as_uint(s[3]); if (!u3) u3 = 1u;
            unsigned long long lo = ((unsigned long long)u1 << 32) | u0;
            unsigned long long hi = ((unsigned long long)u3 << 32) | u2;
            unsigned long long* dst =
                (unsigned long long*)(rbase + (size_t)(t & (DEPTH - 1)) * 1024 + tid * 4);
            __hip_atomic_store(dst,     lo, __ATOMIC_RELAXED, __HIP_MEMORY_SCOPE_AGENT);
            __hip_atomic_store(dst + 1, hi, __ATOMIC_RELAXED, __HIP_MEMORY_SCOPE_AGENT);
        }
        return;
    }

    // ================= consumer role =================
    const int gn  = tid >> 3;
    const int glc = tid & 7;
    const float bi  = bias[0 * HH + hc0 + glc];
    const float bf_ = bias[1 * HH + hc0 + glc];
    const float bo  = bias[2 * HH + hc0 + glc];
    const float bg  = bias[3 * HH + hc0 + glc];
    float creg = 0.f;
    const size_t outoff = (size_t)gn * T_LEN * HH + hc0 + glc;

    unsigned short* u16out = (unsigned short*)out;
    const unsigned short* cbase =
        (const unsigned short*)out + 2 * ((size_t)mrow * T_LEN * HH) + q * 8;
    const size_t stash_w = 2 * ((size_t)gn * T_LEN * HH) + (hc0 + glc);
    const unsigned short* wsrd = ws16 + (size_t)mrow * HH + q * 8;
    const size_t ws_w = (size_t)gn * HH + (hc0 + glc);

    #pragma unroll 1
    for (int t = 0; t < T_LEN; ++t) {
        const float* rp = rbase + (size_t)(t & (DEPTH - 1)) * 1024 + tid * 4;
        bf16x8 hfrag[16];
        i32x4 rv;
        if (t == 0) {
            #pragma unroll
            for (int kk = 0; kk < 16; ++kk)
                hfrag[kk] = cvt8(*(const f32x8*)(h0 + (size_t)mrow * HH + kk * 32 + q * 8));
            rv = poll_ring(rp);
        } else {
            i32x4 f[16];
            if (t < T_LEN - 1)
                poll17(cbase + 2 * (size_t)(t + 1) * HH, rp, f, &rv);  // stash of h_{t-1}
            else
                poll17(wsrd, rp, f, &rv);                              // h_{T-2} from arena
            #pragma unroll
            for (int kk = 0; kk < 16; ++kk) hfrag[kk] = *(bf16x8*)&f[kk];
        }

        // ---- h-part MFMAs (x-part arrives via ring) ----
        f32x4 ac0 = {0,0,0,0}, ac1 = {0,0,0,0}, ac2 = {0,0,0,0}, ac3 = {0,0,0,0};
        #pragma unroll
        for (int kk = 0; kk < 16; ++kk) {
            if (kk & 1) { ac1 = mfma16(hfrag[kk], wbh[kk], ac1); ac3 = mfma16(hfrag[kk], wbl[kk], ac3); }
            else        { ac0 = mfma16(hfrag[kk], wbh[kk], ac0); ac2 = mfma16(hfrag[kk], wbl[kk], ac2); }
        }
        f32x4 av4 = (ac0 + ac1) + (ac2 + ac3);
        av4[0] += __uint_as_float(rv[0]);
        av4[1] += __uint_as_float(rv[1]);
        av4[2] += __uint_as_float(rv[2]);
        av4[3] += __uint_as_float(rv[3]);

        // ---- re-zero the consumed ring slot (keeps data-is-the-flag valid;
        // drained by this wave's own poll at t+1, before progress hits t+1) ----
        {
            unsigned long long* zp = (unsigned long long*)rp;
            __hip_atomic_store(zp,     0ull, __ATOMIC_RELAXED, __HIP_MEMORY_SCOPE_AGENT);
            __hip_atomic_store(zp + 1, 0ull, __ATOMIC_RELAXED, __HIP_MEMORY_SCOPE_AGENT);
        }

        __syncthreads();                 // (1) gates(t-1) done reading a_lds;
                                         //     also: all waves passed poll(t)
        if (tid == 0)                    // slots <= t-1 consumed AND zero-drained
            __hip_atomic_store(progress + blk * FSTRIDE, (unsigned)t,
                               __ATOMIC_RELAXED, __HIP_MEMORY_SCOPE_AGENT);
        #pragma unroll
        for (int r = 0; r < 4; ++r)
            a_lds[(wid & 1) * 16 + q * 4 + r][bcol] = av4[r];
        __syncthreads();                 // (2) a_lds(t) published

        // ---- gates ----
        float ai = a_lds[gn][glc]      + bi;
        float af = a_lds[gn][8 + glc]  + bf_;
        float ao = a_lds[gn][16 + glc] + bo;
        float ag = a_lds[gn][24 + glc] + bg;
        float iv = sigmf_(ai), fv = sigmf_(af), ov = sigmf_(ao);
        float gv = tanhf_(ag);
        creg = fv * creg + iv * gv;
        float hv = ov * tanhf_(creg);

        // ---- pack (intra-wave shuffles; glc = tid&7 so partners same wave) ----
        unsigned hvu = __float_as_uint(hv);
        unsigned long long opair =
            ((unsigned long long)__shfl_xor(hvu, 1) << 32) | (unsigned long long)hvu;
        __bf16 hb = (__bf16)hv;
        unsigned short hus = *(unsigned short*)&hb;
        if (hus == 0) hus = 1;           // +0 -> smallest denormal (poll sentinel)
        unsigned hu = (unsigned)hus;
        unsigned hp = (__shfl_xor(hu, 1) << 16) | hu;
        unsigned long long hq =
            ((unsigned long long)__shfl_xor(hp, 2) << 32) | (unsigned long long)hp;

        // ---- fire-and-forget stores (no drains, no flags) ----
        if ((glc & 1) == 0)
            __hip_atomic_store((unsigned long long*)(out + outoff + (size_t)t * HH),
                               opair, __ATOMIC_RELAXED, __HIP_MEMORY_SCOPE_AGENT);
        if ((glc & 3) == 0) {
            if (t < T_LEN - 2)           // stash h_t into out[:, t+2, :]
                __hip_atomic_store((unsigned long long*)(u16out + stash_w + 2 * (size_t)(t + 2) * HH),
                                   hq, __ATOMIC_RELAXED, __HIP_MEMORY_SCOPE_AGENT);
            else if (t == T_LEN - 2)     // stash h_{T-2} into the d_ws arena
                __hip_atomic_store((unsigned long long*)(ws16 + ws_w),
                                   hq, __ATOMIC_RELAXED, __HIP_MEMORY_SCOPE_AGENT);
        }
    }
}

extern "C" void kernel_launch(void* const* d_in, const int* in_sizes, int n_in,
                              void* d_out, int out_size, void* d_ws, size_t ws_size,
                              hipStream_t stream) {
    const float* x  = (const float*)d_in[0];
    const float* h0 = (const float*)d_in[1];
    const float* Wx = (const float*)d_in[2];
    const float* Wh = (const float*)d_in[3];
    const float* b  = (const float*)d_in[4];
    float* out = (float*)d_out;
    // d_ws layout: [0,32K) h-arena | [32K,34K) progress | [64K, 64K+2M) ring
    unsigned short* ws16 = (unsigned short*)d_ws;
    unsigned* progress   = (unsigned*)((char*)d_ws + 32768);
    float* ring          = (float*)((char*)d_ws + 65536);
    const size_t ring_bytes = (size_t)NBLK * DEPTH * 1024 * sizeof(float);  // 2 MB

    // Self-contained zero-init (data-is-the-flag requires zeroed regions).
    hipMemsetAsync(out, 0, (size_t)32 * T_LEN * HH * sizeof(float), stream);
    hipMemsetAsync(d_ws, 0, 65536 + ring_bytes, stream);
    lstm_pk<<<dim3(2 * NBLK), dim3(256), 0, stream>>>(x, h0, Wx, Wh, b, out,
                                                      ws16, progress, ring);
}